// Round 3
// baseline (75.533 us; speedup 1.0000x reference)
//
#include <hip/hip_runtime.h>

#define HID 1024
#define BATCH 256
#define KTASK 4096
#define TPB 4             // tasks per block (full 256-row batch per block)
#define NCOL (TPB * 8)    // 32 output columns per block
#define KC 32             // k per step
#define NSTEPS (HID / KC) // 32
#define STRIDE 80         // LDS row stride bytes (64 data + 16 pad -> 2-way max)

typedef __bf16 bf16x8 __attribute__((ext_vector_type(8)));
typedef __bf16 bf16x4 __attribute__((ext_vector_type(4)));
typedef float f32x4 __attribute__((ext_vector_type(4)));

static __device__ __forceinline__ bf16x4 cvt4(const float4& a) {
    bf16x4 r;
    r[0] = (__bf16)a.x; r[1] = (__bf16)a.y; r[2] = (__bf16)a.z; r[3] = (__bf16)a.w;
    return r;
}

__global__ __launch_bounds__(256, 4)
void cvt_emb_kernel(const float* __restrict__ emb, __bf16* __restrict__ dst) {
    int i = (blockIdx.x * 256 + threadIdx.x) * 4;
    float4 v = *(const float4*)(emb + i);
    *(bf16x4*)(dst + i) = cvt4(v);
}

__global__ __launch_bounds__(256, 4)
void mtc_kernel(const __bf16* __restrict__ embb, const float* __restrict__ W1,
                const float* __restrict__ b1, const float* __restrict__ W2,
                const float* __restrict__ b2, const int* __restrict__ tids,
                float* __restrict__ out)
{
    __shared__ __align__(16) char wbuf[2][NCOL * STRIDE];   // 5 KB

    const int t = threadIdx.x;
    const int lane = t & 63;
    const int w = t >> 6;
    const int blk = blockIdx.x;          // task-group 0..1023

    // ---- W1 staging: row srow = (task tl, o), k-quarter sq (4 floats each)
    const int srow = t >> 3;             // 0..31
    const int sq   = t & 7;              // 0..7
    const int stask = tids[blk * TPB + (srow >> 3)];
    const float* sgp = W1 + (size_t)stask * (8 * HID) + (size_t)(srow & 7) * HID + sq * 4;
    char* const swr0 = &wbuf[0][0] + srow * STRIDE + sq * 8;
    char* const swr1 = swr0 + NCOL * STRIDE;

    // ---- A fragments: wave w owns rows w*64 .. w*64+63 (4 M-tiles of 16)
    const __bf16* agp = embb + (size_t)(w * 64 + (lane & 15)) * HID + (lane >> 4) * 8;
    const int boff = (lane & 15) * STRIDE + (lane >> 4) * 16;
    const char* const rb0 = &wbuf[0][0];
    const char* const rb1 = &wbuf[1][0];

    f32x4 acc[4][2];
    const f32x4 zero = {0.f, 0.f, 0.f, 0.f};
#pragma unroll
    for (int i = 0; i < 4; ++i)
#pragma unroll
        for (int j = 0; j < 2; ++j) acc[i][j] = zero;

    // ---- prologue: W(0) -> LDS0; W(1) -> slotB; A(0) -> acur
    float4 wa = *(const float4*)(sgp);
    bf16x8 acur[4];
#pragma unroll
    for (int bt = 0; bt < 4; ++bt) acur[bt] = *(const bf16x8*)(agp + (size_t)bt * (16 * HID));
    *(bf16x4*)swr0 = cvt4(wa);
    float4 wb = *(const float4*)(sgp + KC);
    __syncthreads();

    // ---- main loop: 15 double-steps cover s = 0..29 (all prefetches in-bounds)
    for (int i = 0; i < 15; ++i) {
        const int s = 2 * i;
        {   // even s: read buf0, write slotB->buf1, prefetch W(s+2)->slotA, A(s+1)
            wa = *(const float4*)(sgp + (s + 2) * KC);
            bf16x8 an[4];
#pragma unroll
            for (int bt = 0; bt < 4; ++bt)
                an[bt] = *(const bf16x8*)(agp + (s + 1) * KC + (size_t)bt * (16 * HID));
#pragma unroll
            for (int nt = 0; nt < 2; ++nt) {
                bf16x8 bf = *(const bf16x8*)(rb0 + nt * (16 * STRIDE) + boff);
#pragma unroll
                for (int bt = 0; bt < 4; ++bt)
                    acc[bt][nt] = __builtin_amdgcn_mfma_f32_16x16x32_bf16(acur[bt], bf, acc[bt][nt], 0, 0, 0);
            }
            *(bf16x4*)swr1 = cvt4(wb);
#pragma unroll
            for (int bt = 0; bt < 4; ++bt) acur[bt] = an[bt];
            __syncthreads();
        }
        {   // odd s+1: read buf1, write slotA->buf0, prefetch W(s+3)->slotB, A(s+2)
            wb = *(const float4*)(sgp + (s + 3) * KC);
            bf16x8 an[4];
#pragma unroll
            for (int bt = 0; bt < 4; ++bt)
                an[bt] = *(const bf16x8*)(agp + (s + 2) * KC + (size_t)bt * (16 * HID));
#pragma unroll
            for (int nt = 0; nt < 2; ++nt) {
                bf16x8 bf = *(const bf16x8*)(rb1 + nt * (16 * STRIDE) + boff);
#pragma unroll
                for (int bt = 0; bt < 4; ++bt)
                    acc[bt][nt] = __builtin_amdgcn_mfma_f32_16x16x32_bf16(acur[bt], bf, acc[bt][nt], 0, 0, 0);
            }
            *(bf16x4*)swr0 = cvt4(wa);
#pragma unroll
            for (int bt = 0; bt < 4; ++bt) acur[bt] = an[bt];
            __syncthreads();
        }
    }
    {   // s = 30: read buf0, write slotB (=W(31)) -> buf1, A(31)
        bf16x8 an[4];
#pragma unroll
        for (int bt = 0; bt < 4; ++bt)
            an[bt] = *(const bf16x8*)(agp + 31 * KC + (size_t)bt * (16 * HID));
#pragma unroll
        for (int nt = 0; nt < 2; ++nt) {
            bf16x8 bf = *(const bf16x8*)(rb0 + nt * (16 * STRIDE) + boff);
#pragma unroll
            for (int bt = 0; bt < 4; ++bt)
                acc[bt][nt] = __builtin_amdgcn_mfma_f32_16x16x32_bf16(acur[bt], bf, acc[bt][nt], 0, 0, 0);
        }
        *(bf16x4*)swr1 = cvt4(wb);
#pragma unroll
        for (int bt = 0; bt < 4; ++bt) acur[bt] = an[bt];
        __syncthreads();
    }
    {   // s = 31: read buf1, no write, no barrier
#pragma unroll
        for (int nt = 0; nt < 2; ++nt) {
            bf16x8 bf = *(const bf16x8*)(rb1 + nt * (16 * STRIDE) + boff);
#pragma unroll
            for (int bt = 0; bt < 4; ++bt)
                acc[bt][nt] = __builtin_amdgcn_mfma_f32_16x16x32_bf16(acur[bt], bf, acc[bt][nt], 0, 0, 0);
        }
    }

    // ---- epilogue: +b1, relu, *w2, shuffle-reduce over o (8 lanes), +b2, store
    const int col = lane & 15;
    const int rgrp = lane >> 4;
    const int o = col & 7;
#pragma unroll
    for (int nt = 0; nt < 2; ++nt) {
        const int tl = nt * 2 + (col >> 3);       // task-local 0..3
        const int task = tids[blk * TPB + tl];
        const float bb1 = b1[task * 8 + o];
        const float ww2 = W2[task * 8 + o];
#pragma unroll
        for (int bt = 0; bt < 4; ++bt) {
            float v[4];
#pragma unroll
            for (int r = 0; r < 4; ++r) {
                float x = acc[bt][nt][r] + bb1;
                x = x > 0.f ? x : 0.f;
                v[r] = x * ww2;
            }
#pragma unroll
            for (int m = 1; m <= 4; m <<= 1) {
#pragma unroll
                for (int r = 0; r < 4; ++r) v[r] += __shfl_xor(v[r], m, 64);
            }
            if ((lane & 7) == 0) {
                const float bb2 = b2[task];
                const int brow = w * 64 + bt * 16 + rgrp * 4;
                float4 o4 = make_float4(v[0] + bb2, v[1] + bb2, v[2] + bb2, v[3] + bb2);
                *(float4*)(out + (size_t)(blk * TPB + tl) * BATCH + brow) = o4;
            }
        }
    }
}

extern "C" void kernel_launch(void* const* d_in, const int* in_sizes, int n_in,
                              void* d_out, int out_size, void* d_ws, size_t ws_size,
                              hipStream_t stream) {
    const float* emb = (const float*)d_in[0];
    const float* W1  = (const float*)d_in[1];
    const float* b1  = (const float*)d_in[2];
    const float* W2  = (const float*)d_in[3];
    const float* b2  = (const float*)d_in[4];
    const int*   tid = (const int*)d_in[5];
    float* outp = (float*)d_out;
    __bf16* embb = (__bf16*)d_ws;   // 512 KB

    cvt_emb_kernel<<<dim3(BATCH * HID / (256 * 4)), dim3(256), 0, stream>>>(emb, embb);
    mtc_kernel<<<dim3(KTASK / TPB), dim3(256), 0, stream>>>(embb, W1, b1, W2, b2, tid, outp);
}

// Round 4
// 50.091 us; speedup vs baseline: 1.5079x; 1.5079x over previous
//
#include <hip/hip_runtime.h>

#define HID 1024
#define BATCH 256
#define KTASK 4096
#define TPB 8             // tasks per block
#define NCOL (TPB * 8)    // 64 output columns per block
#define KC 32             // k per step
#define NSTEPS (HID / KC) // 32
#define STRIDE 80         // LDS row stride bytes (64 data + 16 pad -> 2-way max)

typedef __bf16 bf16x8 __attribute__((ext_vector_type(8)));
typedef __bf16 bf16x4 __attribute__((ext_vector_type(4)));
typedef float f32x4 __attribute__((ext_vector_type(4)));

static __device__ __forceinline__ bf16x4 cvt4(const float4& a) {
    bf16x4 r;
    r[0] = (__bf16)a.x; r[1] = (__bf16)a.y; r[2] = (__bf16)a.z; r[3] = (__bf16)a.w;
    return r;
}

__global__ __launch_bounds__(256, 4)
void cvt_emb_kernel(const float* __restrict__ emb, __bf16* __restrict__ dst) {
    int i = (blockIdx.x * 256 + threadIdx.x) * 4;
    float4 v = *(const float4*)(emb + i);
    *(bf16x4*)(dst + i) = cvt4(v);
}

// 512 threads = 8 waves; wave w owns rows w*32..+31 (2 M-tiles), all 64 cols.
// Full batch per block -> each W1 row fetched exactly once kernel-wide.
__global__ __launch_bounds__(512, 4)
void mtc_kernel(const __bf16* __restrict__ embb, const float* __restrict__ W1,
                const float* __restrict__ b1, const float* __restrict__ W2,
                const float* __restrict__ b2, const int* __restrict__ tids,
                float* __restrict__ out)
{
    __shared__ __align__(16) char wbuf[2][NCOL * STRIDE];   // 10 KB

    const int t = threadIdx.x;
    const int lane = t & 63;
    const int w = t >> 6;                // 0..7
    const int blk = blockIdx.x;          // task-group 0..511

    // ---- W1 staging: row srow = (task tl, o); k-eighth sq (4 floats each)
    const int srow = t >> 3;             // 0..63
    const int sq   = t & 7;              // 0..7
    const int stask = tids[blk * TPB + (srow >> 3)];
    const float* sgp = W1 + (size_t)stask * (8 * HID) + (size_t)(srow & 7) * HID + sq * 4;
    char* const swr0 = &wbuf[0][0] + srow * STRIDE + sq * 8;
    char* const swr1 = swr0 + NCOL * STRIDE;

    // ---- A fragments: wave w rows w*32 + bt*16 + (lane&15)
    const __bf16* agp = embb + (size_t)(w * 32 + (lane & 15)) * HID + (lane >> 4) * 8;
    const int boff = (lane & 15) * STRIDE + (lane >> 4) * 16;
    const char* const rb0 = &wbuf[0][0];
    const char* const rb1 = &wbuf[1][0];

    f32x4 acc[2][4];
    const f32x4 zero = {0.f, 0.f, 0.f, 0.f};
#pragma unroll
    for (int i = 0; i < 2; ++i)
#pragma unroll
        for (int j = 0; j < 4; ++j) acc[i][j] = zero;

    // ---- prologue: W(0) -> LDS0; W(1) -> slotB; A(0) -> acur
    float4 wa = *(const float4*)(sgp);
    bf16x8 acur0 = *(const bf16x8*)(agp);
    bf16x8 acur1 = *(const bf16x8*)(agp + 16 * HID);
    *(bf16x4*)swr0 = cvt4(wa);
    float4 wb = *(const float4*)(sgp + KC);
    __syncthreads();

    // ---- main loop: 15 double-steps cover s = 0..29 (all prefetches in-bounds)
    for (int i = 0; i < 15; ++i) {
        const int s = 2 * i;
        {   // even s: read buf0, write slotB->buf1, prefetch W(s+2)->slotA, A(s+1)
            wa = *(const float4*)(sgp + (s + 2) * KC);
            bf16x8 an0 = *(const bf16x8*)(agp + (s + 1) * KC);
            bf16x8 an1 = *(const bf16x8*)(agp + (s + 1) * KC + 16 * HID);
#pragma unroll
            for (int nt = 0; nt < 4; ++nt) {
                bf16x8 bf = *(const bf16x8*)(rb0 + nt * (16 * STRIDE) + boff);
                acc[0][nt] = __builtin_amdgcn_mfma_f32_16x16x32_bf16(acur0, bf, acc[0][nt], 0, 0, 0);
                acc[1][nt] = __builtin_amdgcn_mfma_f32_16x16x32_bf16(acur1, bf, acc[1][nt], 0, 0, 0);
            }
            *(bf16x4*)swr1 = cvt4(wb);
            acur0 = an0; acur1 = an1;
            __syncthreads();
        }
        {   // odd s+1: read buf1, write slotA->buf0, prefetch W(s+3)->slotB, A(s+2)
            wb = *(const float4*)(sgp + (s + 3) * KC);
            bf16x8 an0 = *(const bf16x8*)(agp + (s + 2) * KC);
            bf16x8 an1 = *(const bf16x8*)(agp + (s + 2) * KC + 16 * HID);
#pragma unroll
            for (int nt = 0; nt < 4; ++nt) {
                bf16x8 bf = *(const bf16x8*)(rb1 + nt * (16 * STRIDE) + boff);
                acc[0][nt] = __builtin_amdgcn_mfma_f32_16x16x32_bf16(acur0, bf, acc[0][nt], 0, 0, 0);
                acc[1][nt] = __builtin_amdgcn_mfma_f32_16x16x32_bf16(acur1, bf, acc[1][nt], 0, 0, 0);
            }
            *(bf16x4*)swr0 = cvt4(wa);
            acur0 = an0; acur1 = an1;
            __syncthreads();
        }
    }
    {   // s = 30: read buf0, write slotB (=W(31)) -> buf1, A(31)
        bf16x8 an0 = *(const bf16x8*)(agp + 31 * KC);
        bf16x8 an1 = *(const bf16x8*)(agp + 31 * KC + 16 * HID);
#pragma unroll
        for (int nt = 0; nt < 4; ++nt) {
            bf16x8 bf = *(const bf16x8*)(rb0 + nt * (16 * STRIDE) + boff);
            acc[0][nt] = __builtin_amdgcn_mfma_f32_16x16x32_bf16(acur0, bf, acc[0][nt], 0, 0, 0);
            acc[1][nt] = __builtin_amdgcn_mfma_f32_16x16x32_bf16(acur1, bf, acc[1][nt], 0, 0, 0);
        }
        *(bf16x4*)swr1 = cvt4(wb);
        acur0 = an0; acur1 = an1;
        __syncthreads();
    }
    {   // s = 31: read buf1, no write, no barrier
#pragma unroll
        for (int nt = 0; nt < 4; ++nt) {
            bf16x8 bf = *(const bf16x8*)(rb1 + nt * (16 * STRIDE) + boff);
            acc[0][nt] = __builtin_amdgcn_mfma_f32_16x16x32_bf16(acur0, bf, acc[0][nt], 0, 0, 0);
            acc[1][nt] = __builtin_amdgcn_mfma_f32_16x16x32_bf16(acur1, bf, acc[1][nt], 0, 0, 0);
        }
    }

    // ---- epilogue: +b1, relu, *w2, shuffle-reduce over o (8 lanes), +b2, store
    const int col = lane & 15;
    const int rgrp = lane >> 4;
    const int o = col & 7;
#pragma unroll
    for (int nt = 0; nt < 4; ++nt) {
        const int tl = nt * 2 + (col >> 3);       // task-local 0..7
        const int task = tids[blk * TPB + tl];
        const float bb1 = b1[task * 8 + o];
        const float ww2 = W2[task * 8 + o];
#pragma unroll
        for (int bt = 0; bt < 2; ++bt) {
            float v[4];
#pragma unroll
            for (int r = 0; r < 4; ++r) {
                float x = acc[bt][nt][r] + bb1;
                x = x > 0.f ? x : 0.f;
                v[r] = x * ww2;
            }
#pragma unroll
            for (int m = 1; m <= 4; m <<= 1) {
#pragma unroll
                for (int r = 0; r < 4; ++r) v[r] += __shfl_xor(v[r], m, 64);
            }
            if ((lane & 7) == 0) {
                const float bb2 = b2[task];
                const int brow = w * 32 + bt * 16 + rgrp * 4;
                float4 o4 = make_float4(v[0] + bb2, v[1] + bb2, v[2] + bb2, v[3] + bb2);
                *(float4*)(out + (size_t)(blk * TPB + tl) * BATCH + brow) = o4;
            }
        }
    }
}

extern "C" void kernel_launch(void* const* d_in, const int* in_sizes, int n_in,
                              void* d_out, int out_size, void* d_ws, size_t ws_size,
                              hipStream_t stream) {
    const float* emb = (const float*)d_in[0];
    const float* W1  = (const float*)d_in[1];
    const float* b1  = (const float*)d_in[2];
    const float* W2  = (const float*)d_in[3];
    const float* b2  = (const float*)d_in[4];
    const int*   tid = (const int*)d_in[5];
    float* outp = (float*)d_out;
    __bf16* embb = (__bf16*)d_ws;   // 512 KB

    cvt_emb_kernel<<<dim3(BATCH * HID / (256 * 4)), dim3(256), 0, stream>>>(emb, embb);
    mtc_kernel<<<dim3(KTASK / TPB), dim3(512), 0, stream>>>(embb, W1, b1, W2, b2, tid, outp);
}